// Round 1
// baseline (420.975 us; speedup 1.0000x reference)
//
#include <hip/hip_runtime.h>
#include <math.h>

// Problem constants (from reference): B=32, M=16, S=64, Q=48, E=128, D=2E=256
constexpr int Bc = 32, Mc = 16, Sc = 64, Qc = 48, Dc = 256;
constexpr int UPAD = 260; // u_lds padded row stride (floats): breaks stride-256 bank conflict,
                          // keeps 16B alignment (260*4 = 1040 = 65*16)

// One block per (b,m): 512 threads = 8 waves. Each wave owns 8 rows (i).
__global__ __launch_bounds__(512, 1)
void attn_fused(const float* __restrict__ h_g, const float* __restrict__ u_g,
                const float* __restrict__ W, const float* __restrict__ b_g,
                float* __restrict__ out)
{
    __shared__ float u_lds[Qc][UPAD];     // 49,920 B
    __shared__ float h_lds[Sc][Dc];       // 65,536 B
    __shared__ float e_lds[Sc][Qc];       // 12,288 B  exp(s - rowmax)
    __shared__ float whu_lds[Dc];         //  1,024 B
    __shared__ float su_lds[Qc];          // u_j . w_u
    __shared__ float hw_lds[Sc];          // h_i . w_h
    __shared__ float rowmax_lds[Sc];      // max_j s_ij
    __shared__ float rsum_lds[Sc];        // 1/sum_j exp

    const int tid  = threadIdx.x;
    const int lane = tid & 63;
    const int wave = tid >> 6;
    const int bm   = blockIdx.x;          // b*16 + m
    const int b    = bm >> 4;

    const float bias = b_g[0];

    // ---------- phase 1: stage u (padded), h (linear), w_hu ----------
    {
        const float4* ug = (const float4*)(u_g + (size_t)b * Qc * Dc);
        for (int k = tid; k < Qc * (Dc / 4); k += 512) {
            int j = k >> 6, c = k & 63;
            ((float4*)u_lds[j])[c] = ug[k];
        }
        const float4* hg = (const float4*)(h_g + (size_t)bm * Sc * Dc);
        float4* hd = (float4*)&h_lds[0][0];
        for (int k = tid; k < Sc * (Dc / 4); k += 512) hd[k] = hg[k];
        if (tid < Dc / 4) ((float4*)whu_lds)[tid] = ((const float4*)(W + 2 * Dc))[tid];
    }
    __syncthreads();

    // ---------- phase 2: su[j] = u_j.w_u ; hw[i] = h_i.w_h ----------
    {
        const float4 wu4 = ((const float4*)(W + Dc))[lane];   // lane covers d = 4*lane..
        for (int t = 0; t < 6; ++t) {                          // 48 j over 8 waves
            int j = wave + 8 * t;
            float4 uv = ((const float4*)u_lds[j])[lane];
            float p = uv.x * wu4.x + uv.y * wu4.y + uv.z * wu4.z + uv.w * wu4.w;
            for (int o = 32; o > 0; o >>= 1) p += __shfl_xor(p, o);
            if (lane == 0) su_lds[j] = p;
        }
        const float4 wh4 = ((const float4*)W)[lane];
        for (int t = 0; t < 8; ++t) {                          // 64 i over 8 waves
            int i = wave + 8 * t;
            const float4 hv = ((const float4*)&h_lds[i][0])[lane];
            float p = hv.x * wh4.x + hv.y * wh4.y + hv.z * wh4.z + hv.w * wh4.w;
            for (int o = 32; o > 0; o >>= 1) p += __shfl_xor(p, o);
            if (lane == 0) hw_lds[i] = p;
        }
    }
    __syncthreads();

    // ---------- phase 3: s rows (wave w owns i = 8w..8w+7), lane-per-j ----------
    {
        const int i0 = wave * 8;
        const int j  = (lane < Qc) ? lane : 0;   // clamp idle lanes into bounds
        float acc[8] = {0.f, 0.f, 0.f, 0.f, 0.f, 0.f, 0.f, 0.f};
        const float4* urow = (const float4*)u_lds[j];
        const float4* w4   = (const float4*)whu_lds;
        for (int d4 = 0; d4 < Dc / 4; ++d4) {
            float4 uv = urow[d4];
            float4 wv = w4[d4];                   // LDS broadcast
            float4 t;
            t.x = uv.x * wv.x; t.y = uv.y * wv.y; t.z = uv.z * wv.z; t.w = uv.w * wv.w;
#pragma unroll
            for (int r = 0; r < 8; ++r) {
                const float4 hv = ((const float4*)&h_lds[i0 + r][0])[d4];  // broadcast
                acc[r] += hv.x * t.x + hv.y * t.y + hv.z * t.z + hv.w * t.w;
            }
        }
#pragma unroll
        for (int r = 0; r < 8; ++r) {
            const int i = i0 + r;
            float s  = acc[r] + hw_lds[i] + su_lds[j] + bias;
            float sv = (lane < Qc) ? s : -INFINITY;
            float m = sv;
            for (int o = 32; o > 0; o >>= 1) m = fmaxf(m, __shfl_xor(m, o));
            float e = (lane < Qc) ? __expf(sv - m) : 0.f;
            float sum = e;
            for (int o = 32; o > 0; o >>= 1) sum += __shfl_xor(sum, o);
            if (lane < Qc) e_lds[i][lane] = e;
            if (lane == 0) { rowmax_lds[i] = m; rsum_lds[i] = 1.0f / sum; }
        }
    }
    __syncthreads();

    // ---------- phase B: p = softmax_i(rowmax), h_att = sum_i p_i h_i ----------
    // done redundantly per wave (cheap); lane owns d-chunk 4*lane..4*lane+3
    float4 hatt;
    {
        float pm = rowmax_lds[lane];              // i = lane (S==64)
        float mm = pm;
        for (int o = 32; o > 0; o >>= 1) mm = fmaxf(mm, __shfl_xor(mm, o));
        float pe = __expf(pm - mm);
        float ps = pe;
        for (int o = 32; o > 0; o >>= 1) ps += __shfl_xor(ps, o);
        const float pv = pe / ps;                 // p_i for i = lane
        hatt.x = hatt.y = hatt.z = hatt.w = 0.f;
        for (int i = 0; i < Sc; ++i) {
            const float pi = __shfl(pv, i);
            const float4 hv = ((const float4*)&h_lds[i][0])[lane];  // conflict-free
            hatt.x += pi * hv.x; hatt.y += pi * hv.y;
            hatt.z += pi * hv.z; hatt.w += pi * hv.w;
        }
    }

    // ---------- phase C: u_att per row + fused writes ----------
    {
        const int i0 = wave * 8;
        float4* out4 = (float4*)out;
        for (int r = 0; r < 8; ++r) {
            const int i = i0 + r;
            const float rs = rsum_lds[i];
            float4 acc; acc.x = acc.y = acc.z = acc.w = 0.f;
            for (int jj = 0; jj < Qc; ++jj) {
                const float e = e_lds[i][jj];                       // broadcast
                const float4 uv = ((const float4*)u_lds[jj])[lane]; // conflict-free
                acc.x += e * uv.x; acc.y += e * uv.y;
                acc.z += e * uv.z; acc.w += e * uv.w;
            }
            float4 ua; ua.x = acc.x * rs; ua.y = acc.y * rs; ua.z = acc.z * rs; ua.w = acc.w * rs;
            const float4 hv = ((const float4*)&h_lds[i][0])[lane];
            float4 hu; hu.x = hv.x * ua.x; hu.y = hv.y * ua.y; hu.z = hv.z * ua.z; hu.w = hv.w * ua.w;
            float4 hh; hh.x = hv.x * hatt.x; hh.y = hv.y * hatt.y; hh.z = hv.z * hatt.z; hh.w = hv.w * hatt.w;

            const size_t base4 = ((size_t)bm * Sc + i) * (4 * Dc / 4); // 1024 floats/row = 256 f4
            out4[base4 +            lane] = hv;
            out4[base4 +  64 +      lane] = ua;
            out4[base4 + 128 +      lane] = hu;
            out4[base4 + 192 +      lane] = hh;
        }
    }
}

extern "C" void kernel_launch(void* const* d_in, const int* in_sizes, int n_in,
                              void* d_out, int out_size, void* d_ws, size_t ws_size,
                              hipStream_t stream) {
    const float* h = (const float*)d_in[0];   // (B,M,S,D) f32
    const float* u = (const float*)d_in[1];   // (B,Q,D) f32
    const float* W = (const float*)d_in[2];   // (3D,) f32
    const float* b = (const float*)d_in[3];   // (1,) f32
    // d_in[4] = is_train (ignored, == 0)
    float* out = (float*)d_out;               // (B,M,S,4D) f32

    attn_fused<<<dim3(Bc * Mc), dim3(512), 0, stream>>>(h, u, W, b, out);
}